// Round 5
// baseline (88.793 us; speedup 1.0000x reference)
//
#include <hip/hip_runtime.h>

#define NBINS 15
#define NSLOT 256      // spread factor for global histogram atomics
#define SSTR  48       // slot stride in floats (>= 3*NBINS)
#define NC    100      // classes

// 4 lanes per row: lane q of a quad reads float4s {q, q+4, ..., q+20} (+ #24
// on q==0). Per wave instruction: 16 contiguous 64B segments at 400B stride
// -> fully-utilized cache lines, no LDS staging, high occupancy.
__global__ __launch_bounds__(256) void ece_main(
    const float* __restrict__ logits,
    const int* __restrict__ labels,
    float* __restrict__ ws, int N) {
  __shared__ float s_hist[3 * NBINS];
  const int tid = threadIdx.x;
  if (tid < 3 * NBINS) s_hist[tid] = 0.f;
  __syncthreads();

  const int q = tid & 3;
  const int row = blockIdx.x * 64 + (tid >> 2);
  if (row < N) {
    const float4* rp4 = (const float4*)(logits + (long long)row * NC);

    float4 f[7];
    #pragma unroll
    for (int j = 0; j < 6; ++j) f[j] = rp4[q + 4 * j];
    f[6] = make_float4(-INFINITY, -INFINITY, -INFINITY, -INFINITY);
    if (q == 0) f[6] = rp4[24];          // tail float4 (elements 96..99)

    // per-component argmax chains; k = float4 index, element = 4k + comp
    float bx = f[0].x, by = f[0].y, bz = f[0].z, bw = f[0].w;
    int kx = q, ky = q, kz = q, kw = q;
    #pragma unroll
    for (int j = 1; j < 7; ++j) {
      const int k = (j < 6) ? (q + 4 * j) : 24;
      if (f[j].x > bx) { bx = f[j].x; kx = k; }
      if (f[j].y > by) { by = f[j].y; ky = k; }
      if (f[j].z > bz) { bz = f[j].z; kz = k; }
      if (f[j].w > bw) { bw = f[j].w; kw = k; }
    }
    // merge components: value desc, element index asc (first occurrence)
    float m = bx; int mi = 4 * kx;
    if (by > m || (by == m && 4 * ky + 1 < mi)) { m = by; mi = 4 * ky + 1; }
    if (bz > m || (bz == m && 4 * kz + 2 < mi)) { m = bz; mi = 4 * kz + 2; }
    if (bw > m || (bw == m && 4 * kw + 3 < mi)) { m = bw; mi = 4 * kw + 3; }

    // merge across the quad (xor 1, 2): short dependent chain
    #pragma unroll
    for (int off = 1; off <= 2; off <<= 1) {
      float ov = __shfl_xor(m, off);
      int   oi = __shfl_xor(mi, off);
      if (ov > m || (ov == m && oi < mi)) { m = ov; mi = oi; }
    }

    // partial exp-sum with the global row max (f[6] = -inf lanes add 0)
    float sx = 0.f, sy = 0.f, sz = 0.f, sw = 0.f;
    #pragma unroll
    for (int j = 0; j < 7; ++j) {
      sx += __expf(f[j].x - m);
      sy += __expf(f[j].y - m);
      sz += __expf(f[j].z - m);
      sw += __expf(f[j].w - m);
    }
    float s = (sx + sy) + (sz + sw);
    #pragma unroll
    for (int off = 1; off <= 2; off <<= 1) s += __shfl_xor(s, off);

    if (q == 0) {
      float conf = 1.0f / s;
      int b = (int)ceilf(conf * (float)NBINS) - 1;
      b = b < 0 ? 0 : (b > NBINS - 1 ? NBINS - 1 : b);
      float acc = (mi == labels[row]) ? 1.0f : 0.0f;
      atomicAdd(&s_hist[b], 1.0f);
      atomicAdd(&s_hist[NBINS + b], conf);
      atomicAdd(&s_hist[2 * NBINS + b], acc);
    }
  }
  __syncthreads();

  if (tid < 3 * NBINS) {
    float v = s_hist[tid];
    if (v != 0.f)
      atomicAdd(&ws[(blockIdx.x & (NSLOT - 1)) * SSTR + tid], v);
  }
}

__global__ void ece_final(const float* __restrict__ ws,
                          float* __restrict__ out, int N) {
  __shared__ float per_bin[NBINS];
  const int b = threadIdx.x;
  if (b < NBINS) {
    float cnt = 0.f, cf = 0.f, ac = 0.f;
    #pragma unroll 8
    for (int s = 0; s < NSLOT; ++s) {
      cnt += ws[s * SSTR + b];
      cf  += ws[s * SSTR + NBINS + b];
      ac  += ws[s * SSTR + 2 * NBINS + b];
    }
    float d = fmaxf(cnt, 1.0f);
    per_bin[b] = (cnt > 0.f) ? fabsf(cf / d - ac / d) * (cnt / (float)N) : 0.f;
  }
  __syncthreads();
  if (b == 0) {
    float e = 0.f;
    #pragma unroll
    for (int i = 0; i < NBINS; ++i) e += per_bin[i];
    out[0] = e;
  }
}

extern "C" void kernel_launch(void* const* d_in, const int* in_sizes, int n_in,
                              void* d_out, int out_size, void* d_ws, size_t ws_size,
                              hipStream_t stream) {
  const float* logits = (const float*)d_in[0];
  const int* labels = (const int*)d_in[1];
  const int N = in_sizes[1];
  float* ws = (float*)d_ws;
  float* out = (float*)d_out;

  hipMemsetAsync(ws, 0, NSLOT * SSTR * sizeof(float), stream);
  const int grid = (N + 63) / 64;          // 64 rows per 256-thread block
  ece_main<<<grid, 256, 0, stream>>>(logits, labels, ws, N);
  ece_final<<<1, 64, 0, stream>>>(ws, out, N);
}